// Round 3
// baseline (957.871 us; speedup 1.0000x reference)
//
#include <hip/hip_runtime.h>
#include <hip/hip_bf16.h>
#include <stdint.h>
#include <type_traits>

// Problem constants: B=256, T=512, D=300, H=128, 4H=512, C=6
#define NB 256
#define NT 512
#define ND 300
#define NH 128
#define NG 512
#define NC 6

typedef __attribute__((ext_vector_type(8))) short short8;
typedef __attribute__((ext_vector_type(4))) float f32x4;

static __device__ __forceinline__ float bf2f(unsigned int u) {
  return __builtin_bit_cast(float, (u & 0xffffu) << 16);
}
static __device__ __forceinline__ unsigned short f2bf(float f) {
  return __builtin_bit_cast(unsigned short, __float2bfloat16(f));
}
static __device__ __forceinline__ float ld1(const unsigned short* p) { return bf2f(*p); }
static __device__ __forceinline__ float ld1(const float* p) { return *p; }
static __device__ __forceinline__ void st1(unsigned short* p, float v) { *p = f2bf(v); }
static __device__ __forceinline__ void st1(float* p, float v) { *p = v; }

static __device__ __forceinline__ float sigmoid_fast(float x) {
  return __builtin_amdgcn_rcpf(1.f + __expf(-x));
}
static __device__ __forceinline__ float tanh_fast(float x) {
  return 1.f - 2.f * __builtin_amdgcn_rcpf(__expf(2.f * x) + 1.f);
}

// Load 4 consecutive K-elements (zero-padded past lim) as 2 packed bf16 pairs.
static __device__ __forceinline__ uint2 load4bf(const unsigned short* row, int k, int lim) {
  uint2 v;
  if (k + 3 < lim) {
    v = *(const uint2*)(row + k);  // 8B-aligned: (row*300+k)*2, k%4==0, 300%4==0
  } else {
    unsigned int e0 = (k + 0 < lim) ? row[k + 0] : 0;
    unsigned int e1 = (k + 1 < lim) ? row[k + 1] : 0;
    unsigned int e2 = (k + 2 < lim) ? row[k + 2] : 0;
    unsigned int e3 = (k + 3 < lim) ? row[k + 3] : 0;
    v.x = e0 | (e1 << 16);
    v.y = e2 | (e3 << 16);
  }
  return v;
}
static __device__ __forceinline__ uint2 load4bf(const float* row, int k, int lim) {
  float f0 = 0.f, f1 = 0.f, f2 = 0.f, f3 = 0.f;
  if (k + 3 < lim) {
    float4 f = *(const float4*)(row + k);  // 16B-aligned: (row*300+k)*4, k%4==0
    f0 = f.x; f1 = f.y; f2 = f.z; f3 = f.w;
  } else {
    if (k + 0 < lim) f0 = row[k + 0];
    if (k + 1 < lim) f1 = row[k + 1];
    if (k + 2 < lim) f2 = row[k + 2];
    if (k + 3 < lim) f3 = row[k + 3];
  }
  uint2 v;
  v.x = (unsigned int)f2bf(f0) | ((unsigned int)f2bf(f1) << 16);
  v.y = (unsigned int)f2bf(f2) | ((unsigned int)f2bf(f3) << 16);
  return v;
}

// ---------------------------------------------------------------------------
// Dtype detector: true-bf16 N(0,1) data has ~100% plausible exponents;
// fp32 read as uint16 has ~62% (odd halfwords are random mantissa bits).
// flag: 0 = inputs are bf16, 1 = inputs are fp32.
// ---------------------------------------------------------------------------
__global__ void detect_dtype(const unsigned short* __restrict__ X, int* __restrict__ flag) {
  __shared__ int cnt;
  if (threadIdx.x == 0) cnt = 0;
  __syncthreads();
  int c = 0;
  for (int i = threadIdx.x; i < 512; i += 64) {
    unsigned int u = X[i];
    unsigned int e = (u >> 7) & 0xffu;
    if (u == 0u || (e >= 97u && e <= 157u)) c++;  // |v| in [2^-30, 2^30] or +0
  }
  atomicAdd(&cnt, c);
  __syncthreads();
  if (threadIdx.x == 0) *flag = (cnt >= 448) ? 0 : 1;
}

// ---------------------------------------------------------------------------
// Phase 1: gx[m][n] = sum_k x[b,t,k] * W_ih[n][k] for a (b,t) chunk.
// Block tile 128(M) x 64(N), 4 waves (2x2), MFMA 16x16x32 bf16, K 300->320.
// ---------------------------------------------------------------------------
template <typename XT, typename GXT>
__global__ __launch_bounds__(256) void gx_gemm(const int* __restrict__ flag, int want,
                                               const XT* __restrict__ X,
                                               const XT* __restrict__ Wih,
                                               const int* __restrict__ lengths,
                                               GXT* __restrict__ gx,
                                               int b_base, int t_base, int Tc) {
  if (*flag != want) return;  // block-uniform dtype dispatch
  const int nb = blockIdx.x;
  const int mb = blockIdx.y;
  const int m0 = mb << 7;
  const int bc = m0 / Tc;     // Tc is a multiple of 128: tile within one batch elem
  const int trel0 = m0 % Tc;
  const int b = b_base + bc;
  const int t0 = t_base + trel0;
  const int len = lengths[b];
  if (t0 >= len) return;      // rows never consumed
  const int n0 = nb << 6;

  __shared__ unsigned short As[128][40];
  __shared__ unsigned short Bs[64][40];

  const int tid = threadIdx.x;
  const int lane = tid & 63;
  const int wave = tid >> 6;
  const int wm = wave & 1;
  const int wn = wave >> 1;
  const int lq = lane >> 4;
  const int lr = lane & 15;

  const int rA = tid >> 1, cA = (tid & 1) * 16;
  const int rB = tid >> 2, cB = (tid & 3) * 8;
  const XT* xrow = X + ((size_t)b * NT + t0 + rA) * ND;
  const XT* wrow = Wih + (size_t)(n0 + rB) * ND;

  f32x4 acc[4][2];
#pragma unroll
  for (int i = 0; i < 4; ++i)
#pragma unroll
    for (int j = 0; j < 2; ++j) {
      f32x4 z = {0.f, 0.f, 0.f, 0.f};
      acc[i][j] = z;
    }

  for (int kc = 0; kc < 320; kc += 32) {
    __syncthreads();
#pragma unroll
    for (int g4 = 0; g4 < 4; ++g4)
      *(uint2*)&As[rA][cA + g4 * 4] = load4bf(xrow, kc + cA + g4 * 4, ND);
#pragma unroll
    for (int g4 = 0; g4 < 2; ++g4)
      *(uint2*)&Bs[rB][cB + g4 * 4] = load4bf(wrow, kc + cB + g4 * 4, ND);
    __syncthreads();

    short8 af[4], bq[2];
#pragma unroll
    for (int tm = 0; tm < 4; ++tm)
      af[tm] = *(const short8*)&As[wm * 64 + tm * 16 + lr][lq * 8];
#pragma unroll
    for (int tn = 0; tn < 2; ++tn)
      bq[tn] = *(const short8*)&Bs[wn * 32 + tn * 16 + lr][lq * 8];
#pragma unroll
    for (int tm = 0; tm < 4; ++tm)
#pragma unroll
      for (int tn = 0; tn < 2; ++tn)
        acc[tm][tn] =
            __builtin_amdgcn_mfma_f32_16x16x32_bf16(af[tm], bq[tn], acc[tm][tn], 0, 0, 0);
  }

  // C/D layout: col = lane&15, row = (lane>>4)*4 + reg
#pragma unroll
  for (int tm = 0; tm < 4; ++tm)
#pragma unroll
    for (int tn = 0; tn < 2; ++tn)
#pragma unroll
      for (int rg = 0; rg < 4; ++rg) {
        const int tileRow = wm * 64 + tm * 16 + lq * 4 + rg;
        if (t0 + tileRow < len) {
          const int col = n0 + wn * 32 + tn * 16 + lr;
          st1(gx + (size_t)(m0 + tileRow) * NG + col, acc[tm][tn][rg]);
        }
      }
}

// ---------------------------------------------------------------------------
// Phase 2: per-batch recurrence over t in [t_base, min(len, t_base+Tc)).
// 512 threads; thread r owns W_hh row r in fp32 registers; h fp32 in LDS.
// Chunk-LOCAL h/c state (indexed by bc) persists across t-chunks in ws.
// ---------------------------------------------------------------------------
template <typename XT, typename GXT>
__global__ __launch_bounds__(512) void lstm_rec(const int* __restrict__ flag, int want,
                                                const GXT* __restrict__ gx,
                                                const XT* __restrict__ Whh,
                                                const XT* __restrict__ bih,
                                                const XT* __restrict__ bhh,
                                                const XT* __restrict__ fcw,
                                                const XT* __restrict__ fcb,
                                                const int* __restrict__ lengths,
                                                XT* __restrict__ out,
                                                float* __restrict__ hstate,
                                                float* __restrict__ cstate,
                                                int b_base, int t_base, int Tc) {
  if (*flag != want) return;  // block-uniform dtype dispatch
  const int bc = blockIdx.x;
  const int b = b_base + bc;
  int len = lengths[b];
  if (len > NT) len = NT;
  if (len < 0) len = 0;
  const bool first = (t_base == 0);
  const bool last = (t_base + Tc >= NT);
  const int tend = (len < t_base + Tc) ? len : (t_base + Tc);
  if (!last && tend <= t_base) return;  // no steps; state untouched

  const int r = threadIdx.x;

  __shared__ float act[NG];
  __shared__ __align__(16) float hf[NH];

  float2 w[64];  // W_hh row r
  if constexpr (std::is_same_v<XT, unsigned short>) {
    const uint4* wp = (const uint4*)Whh + (size_t)r * 16;
#pragma unroll
    for (int i = 0; i < 16; ++i) {
      uint4 v = wp[i];
      w[4 * i + 0] = make_float2(bf2f(v.x), bf2f(v.x >> 16));
      w[4 * i + 1] = make_float2(bf2f(v.y), bf2f(v.y >> 16));
      w[4 * i + 2] = make_float2(bf2f(v.z), bf2f(v.z >> 16));
      w[4 * i + 3] = make_float2(bf2f(v.w), bf2f(v.w >> 16));
    }
  } else {
    const float4* wp = (const float4*)(Whh + (size_t)r * NH);
#pragma unroll
    for (int i = 0; i < 32; ++i) {
      float4 v = wp[i];
      w[2 * i + 0] = make_float2(v.x, v.y);
      w[2 * i + 1] = make_float2(v.z, v.w);
    }
  }

  const float bias = ld1(bih + r) + ld1(bhh + r);

  float cst = 0.f;
  if (r < NH) {
    float hv = 0.f;
    if (!first) {
      hv = hstate[(size_t)bc * NH + r];
      cst = cstate[(size_t)bc * NH + r];
    }
    hf[r] = hv;
  }
  __syncthreads();

  const GXT* gxc = gx + (size_t)bc * Tc * NG + r;
  float g_cur = (t_base < tend) ? ld1(gxc) : 0.f;
  float g_n1 = (t_base + 1 < tend) ? ld1(gxc + NG) : 0.f;

  for (int t = t_base; t < tend; ++t) {
    float g_n2 = (t + 2 < tend) ? ld1(gxc + (size_t)(t + 2 - t_base) * NG) : 0.f;

    float a0 = 0.f, a1 = 0.f, a2 = 0.f, a3 = 0.f;
    const float4* hp = (const float4*)hf;
#pragma unroll
    for (int i = 0; i < 32; ++i) {
      float4 hv = hp[i];  // broadcast ds_read_b128
      a0 = fmaf(w[2 * i].x, hv.x, a0);
      a1 = fmaf(w[2 * i].y, hv.y, a1);
      a2 = fmaf(w[2 * i + 1].x, hv.z, a2);
      a3 = fmaf(w[2 * i + 1].y, hv.w, a3);
    }
    const float gate = g_cur + bias + ((a0 + a1) + (a2 + a3));
    const float v = (r >= 2 * NH && r < 3 * NH) ? tanh_fast(gate) : sigmoid_fast(gate);
    act[r] = v;
    __syncthreads();
    if (r < NH) {
      const float ig = act[r], fg = act[NH + r], gg = act[2 * NH + r], og = act[3 * NH + r];
      cst = fg * cst + ig * gg;
      hf[r] = og * tanh_fast(cst);
    }
    __syncthreads();
    g_cur = g_n1;
    g_n1 = g_n2;
  }

  if (!last) {
    if (r < NH) {
      hstate[(size_t)bc * NH + r] = hf[r];
      cstate[(size_t)bc * NH + r] = cst;
    }
  } else if (r < NC) {
    float acc = ld1(fcb + r);
    const XT* wv = fcw + (size_t)r * NH;
#pragma unroll
    for (int k = 0; k < NH; ++k) acc = fmaf(ld1(wv + k), hf[k], acc);
    st1(out + (size_t)b * NC + r, acc);
  }
}

// ---------------------------------------------------------------------------
template <typename XT, typename GXT>
static void run_variant(int want, const int* flag, void* const* d_in, XT* out,
                        GXT* gx, float* hstate, float* cstate, int NBc, int Tc,
                        hipStream_t stream) {
  const XT* X = (const XT*)d_in[0];
  const XT* Wih = (const XT*)d_in[1];
  const XT* Whh = (const XT*)d_in[2];
  const XT* bih = (const XT*)d_in[3];
  const XT* bhh = (const XT*)d_in[4];
  const XT* fcw = (const XT*)d_in[5];
  const XT* fcb = (const XT*)d_in[6];
  const int* lengths = (const int*)d_in[7];
  for (int bb = 0; bb < NB; bb += NBc) {
    for (int tb = 0; tb < NT; tb += Tc) {
      gx_gemm<XT, GXT><<<dim3(NG / 64, (NBc * Tc) / 128), dim3(256), 0, stream>>>(
          flag, want, X, Wih, lengths, gx, bb, tb, Tc);
      lstm_rec<XT, GXT><<<dim3(NBc), dim3(512), 0, stream>>>(
          flag, want, gx, Whh, bih, bhh, fcw, fcb, lengths, out, hstate, cstate, bb, tb, Tc);
    }
  }
}

extern "C" void kernel_launch(void* const* d_in, const int* in_sizes, int n_in,
                              void* d_out, int out_size, void* d_ws, size_t ws_size,
                              hipStream_t stream) {
  int* flag = (int*)d_ws;  // ws+0: dtype flag (recomputed every call)
  detect_dtype<<<dim3(1), dim3(64), 0, stream>>>((const unsigned short*)d_in[0], flag);

  const size_t full_f32 = (size_t)NB * NT * NG * sizeof(float);  // 256 MiB
  const size_t full_bf16 = (size_t)NB * NT * NG * 2;             // 128 MiB
  const size_t base = 512;

  int NBc, Tc;
  char* gx_raw;
  float* hstate = (float*)((char*)d_ws + base);  // chunk-local state (<=256 KB)
  bool gx_is_f32;

  if (ws_size >= base + full_f32) {
    NBc = NB; Tc = NT; gx_is_f32 = true;
    gx_raw = (char*)d_ws + base;  // single chunk: state never used
  } else if (ws_size >= base + full_bf16) {
    NBc = NB; Tc = NT; gx_is_f32 = false;
    gx_raw = (char*)d_ws + base;
  } else {
    Tc = 128; gx_is_f32 = false;
    NBc = 1;
    for (int cand : {64, 16, 4}) {
      size_t need = base + (size_t)cand * NH * 2 * sizeof(float) + (size_t)cand * Tc * NG * 2;
      if (ws_size >= need) { NBc = cand; break; }
    }
    gx_raw = (char*)d_ws + base + (size_t)NBc * NH * 2 * sizeof(float);
  }
  float* cstate = hstate + (size_t)NBc * NH;

  if (gx_is_f32) {
    run_variant<unsigned short, float>(0, flag, d_in, (unsigned short*)d_out,
                                       (float*)gx_raw, hstate, cstate, NBc, Tc, stream);
    run_variant<float, float>(1, flag, d_in, (float*)d_out, (float*)gx_raw, hstate,
                              cstate, NBc, Tc, stream);
  } else {
    run_variant<unsigned short, unsigned short>(0, flag, d_in, (unsigned short*)d_out,
                                                (unsigned short*)gx_raw, hstate, cstate,
                                                NBc, Tc, stream);
    run_variant<float, unsigned short>(1, flag, d_in, (float*)d_out,
                                       (unsigned short*)gx_raw, hstate, cstate, NBc, Tc,
                                       stream);
  }
}

// Round 4
// 668.731 us; speedup vs baseline: 1.4324x; 1.4324x over previous
//
#include <hip/hip_runtime.h>
#include <hip/hip_bf16.h>
#include <stdint.h>
#include <type_traits>

// Problem constants: B=256, T=512, D=300, H=128, 4H=512, C=6
#define NB 256
#define NT 512
#define ND 300
#define NH 128
#define NG 512
#define NC 6

typedef __attribute__((ext_vector_type(8))) short short8;
typedef __attribute__((ext_vector_type(4))) float f32x4;

#if __has_builtin(__builtin_amdgcn_fdot2_f32_bf16)
#define HAS_DOT2 1
typedef __attribute__((ext_vector_type(2))) __bf16 bf16x2_t;
static __device__ __forceinline__ float dot2bf(unsigned int wp, unsigned int hp, float acc) {
  return __builtin_amdgcn_fdot2_f32_bf16(__builtin_bit_cast(bf16x2_t, wp),
                                         __builtin_bit_cast(bf16x2_t, hp), acc, false);
}
#else
static __device__ __forceinline__ float dot2bf(unsigned int wp, unsigned int hp, float acc) {
  float wl = __builtin_bit_cast(float, wp << 16);
  float wh = __builtin_bit_cast(float, wp & 0xffff0000u);
  float hl = __builtin_bit_cast(float, hp << 16);
  float hh = __builtin_bit_cast(float, hp & 0xffff0000u);
  return fmaf(wh, hh, fmaf(wl, hl, acc));
}
#endif

static __device__ __forceinline__ float bf2f(unsigned int u) {
  return __builtin_bit_cast(float, (u & 0xffffu) << 16);
}
static __device__ __forceinline__ unsigned short f2bf(float f) {
  return __builtin_bit_cast(unsigned short, __float2bfloat16(f));
}
static __device__ __forceinline__ unsigned int packbf(float a, float b) {
  return (unsigned int)f2bf(a) | ((unsigned int)f2bf(b) << 16);
}
static __device__ __forceinline__ float ld1(const unsigned short* p) { return bf2f(*p); }
static __device__ __forceinline__ float ld1(const float* p) { return *p; }
static __device__ __forceinline__ void st1(unsigned short* p, float v) { *p = f2bf(v); }
static __device__ __forceinline__ void st1(float* p, float v) { *p = v; }

static __device__ __forceinline__ float tanh_fast(float x) {
  return 1.f - 2.f * __builtin_amdgcn_rcpf(__expf(2.f * x) + 1.f);
}

// Load 4 consecutive K-elements (zero-padded past lim) as 2 packed bf16 pairs.
static __device__ __forceinline__ uint2 load4bf(const unsigned short* row, int k, int lim) {
  uint2 v;
  if (k + 3 < lim) {
    v = *(const uint2*)(row + k);
  } else {
    unsigned int e0 = (k + 0 < lim) ? row[k + 0] : 0;
    unsigned int e1 = (k + 1 < lim) ? row[k + 1] : 0;
    unsigned int e2 = (k + 2 < lim) ? row[k + 2] : 0;
    unsigned int e3 = (k + 3 < lim) ? row[k + 3] : 0;
    v.x = e0 | (e1 << 16);
    v.y = e2 | (e3 << 16);
  }
  return v;
}
static __device__ __forceinline__ uint2 load4bf(const float* row, int k, int lim) {
  float f0 = 0.f, f1 = 0.f, f2 = 0.f, f3 = 0.f;
  if (k + 3 < lim) {
    float4 f = *(const float4*)(row + k);
    f0 = f.x; f1 = f.y; f2 = f.z; f3 = f.w;
  } else {
    if (k + 0 < lim) f0 = row[k + 0];
    if (k + 1 < lim) f1 = row[k + 1];
    if (k + 2 < lim) f2 = row[k + 2];
    if (k + 3 < lim) f3 = row[k + 3];
  }
  uint2 v;
  v.x = packbf(f0, f1);
  v.y = packbf(f2, f3);
  return v;
}

// ---------------------------------------------------------------------------
// Dtype detector (flag: 0 = bf16 inputs, 1 = fp32 inputs).
// ---------------------------------------------------------------------------
__global__ void detect_dtype(const unsigned short* __restrict__ X, int* __restrict__ flag) {
  __shared__ int cnt;
  if (threadIdx.x == 0) cnt = 0;
  __syncthreads();
  int c = 0;
  for (int i = threadIdx.x; i < 512; i += 64) {
    unsigned int u = X[i];
    unsigned int e = (u >> 7) & 0xffu;
    if (u == 0u || (e >= 97u && e <= 157u)) c++;
  }
  atomicAdd(&cnt, c);
  __syncthreads();
  if (threadIdx.x == 0) *flag = (cnt >= 448) ? 0 : 1;
}

// ---------------------------------------------------------------------------
// Phase 1: gx[m][n] = sum_k x[b,t,k] * W_ih[n][k].
// One block per 128-row M tile; loops all 8 N-tiles internally so the block's
// X rows are HBM-read once and L2-served for the other 7 tiles.
// ---------------------------------------------------------------------------
template <typename XT, typename GXT>
__global__ __launch_bounds__(256) void gx_gemm(const int* __restrict__ flag, int want,
                                               const XT* __restrict__ X,
                                               const XT* __restrict__ Wih,
                                               const int* __restrict__ lengths,
                                               GXT* __restrict__ gx,
                                               int b_base, int t_base, int Tc) {
  if (*flag != want) return;
  const int mb = blockIdx.x;
  const int m0 = mb << 7;
  const int bc = m0 / Tc;
  const int trel0 = m0 % Tc;
  const int b = b_base + bc;
  const int t0 = t_base + trel0;
  const int len = lengths[b];
  if (t0 >= len) return;

  __shared__ unsigned short As[128][40];
  __shared__ unsigned short Bs[64][40];

  const int tid = threadIdx.x;
  const int lane = tid & 63;
  const int wave = tid >> 6;
  const int wm = wave & 1;
  const int wn = wave >> 1;
  const int lq = lane >> 4;
  const int lr = lane & 15;

  const int rA = tid >> 1, cA = (tid & 1) * 16;
  const int rB = tid >> 2, cB = (tid & 3) * 8;
  const XT* xrow = X + ((size_t)b * NT + t0 + rA) * ND;

  for (int nt = 0; nt < 8; ++nt) {
    const int n0 = nt << 6;
    const XT* wrow = Wih + (size_t)(n0 + rB) * ND;

    f32x4 acc[4][2];
#pragma unroll
    for (int i = 0; i < 4; ++i)
#pragma unroll
      for (int j = 0; j < 2; ++j) {
        f32x4 z = {0.f, 0.f, 0.f, 0.f};
        acc[i][j] = z;
      }

    for (int kc = 0; kc < 320; kc += 32) {
      __syncthreads();
#pragma unroll
      for (int g4 = 0; g4 < 4; ++g4)
        *(uint2*)&As[rA][cA + g4 * 4] = load4bf(xrow, kc + cA + g4 * 4, ND);
#pragma unroll
      for (int g4 = 0; g4 < 2; ++g4)
        *(uint2*)&Bs[rB][cB + g4 * 4] = load4bf(wrow, kc + cB + g4 * 4, ND);
      __syncthreads();

      short8 af[4], bq[2];
#pragma unroll
      for (int tm = 0; tm < 4; ++tm)
        af[tm] = *(const short8*)&As[wm * 64 + tm * 16 + lr][lq * 8];
#pragma unroll
      for (int tn = 0; tn < 2; ++tn)
        bq[tn] = *(const short8*)&Bs[wn * 32 + tn * 16 + lr][lq * 8];
#pragma unroll
      for (int tm = 0; tm < 4; ++tm)
#pragma unroll
        for (int tn = 0; tn < 2; ++tn)
          acc[tm][tn] =
              __builtin_amdgcn_mfma_f32_16x16x32_bf16(af[tm], bq[tn], acc[tm][tn], 0, 0, 0);
    }

    // C/D layout: col = lane&15, row = (lane>>4)*4 + reg
#pragma unroll
    for (int tm = 0; tm < 4; ++tm)
#pragma unroll
      for (int tn = 0; tn < 2; ++tn)
#pragma unroll
        for (int rg = 0; rg < 4; ++rg) {
          const int tileRow = wm * 64 + tm * 16 + lq * 4 + rg;
          if (t0 + tileRow < len) {
            const int col = n0 + wn * 32 + tn * 16 + lr;
            st1(gx + (size_t)(m0 + tileRow) * NG + col, acc[tm][tn][rg]);
          }
        }
  }
}

// ---------------------------------------------------------------------------
// Phase 2: per-batch recurrence, shuffle-combined gates, packed-bf16 h.
// Thread (wave w, lane l): gate g = l>>4, unit = w*16 + (l&15),
// row = g*128 + unit. W_hh row packed in 64 uint regs. Per step:
//   read hpk[s&1] (16 ds_read_b128, broadcast) -> 64 dot2 -> activation
//   -> 3 shfl_xor puts all 4 gates in g==0 lanes -> c/h update
//   -> masked bf16 h write to hpk[(s+1)&1] -> ONE barrier.
// ---------------------------------------------------------------------------
template <typename XT, typename GXT>
__global__ __launch_bounds__(512, 2) void lstm_rec(const int* __restrict__ flag, int want,
                                                   const GXT* __restrict__ gx,
                                                   const XT* __restrict__ Whh,
                                                   const XT* __restrict__ bih,
                                                   const XT* __restrict__ bhh,
                                                   const XT* __restrict__ fcw,
                                                   const XT* __restrict__ fcb,
                                                   const int* __restrict__ lengths,
                                                   XT* __restrict__ out,
                                                   float* __restrict__ hstate,
                                                   float* __restrict__ cstate,
                                                   int b_base, int t_base, int Tc) {
  if (*flag != want) return;
  const int bc = blockIdx.x;
  const int b = b_base + bc;
  int len = lengths[b];
  if (len > NT) len = NT;
  if (len < 0) len = 0;
  const bool first = (t_base == 0);
  const bool last = (t_base + Tc >= NT);
  const int tend = (len < t_base + Tc) ? len : (t_base + Tc);
  if (!last && tend <= t_base) return;  // no steps; ws state untouched

  const int tid = threadIdx.x;
  const int w8 = tid >> 6;
  const int l = tid & 63;
  const int g = l >> 4;
  const int unit = w8 * 16 + (l & 15);
  const int row = g * NH + unit;

  __shared__ __align__(16) unsigned short hpk[2][NH];  // double-buffered packed h
  __shared__ __align__(16) float hf[NH];               // final h (FC epilogue)

  // W_hh row as 64 packed bf16 pairs in registers.
  unsigned int w2[64];
  if constexpr (std::is_same_v<XT, unsigned short>) {
    const uint4* wp = (const uint4*)Whh + (size_t)row * 16;
#pragma unroll
    for (int i = 0; i < 16; ++i) {
      uint4 v = wp[i];
      w2[4 * i + 0] = v.x;
      w2[4 * i + 1] = v.y;
      w2[4 * i + 2] = v.z;
      w2[4 * i + 3] = v.w;
    }
  } else {
    const float4* wp = (const float4*)(Whh + (size_t)row * NH);
#pragma unroll
    for (int i = 0; i < 32; ++i) {
      float4 v = wp[i];
      w2[2 * i + 0] = packbf(v.x, v.y);
      w2[2 * i + 1] = packbf(v.z, v.w);
    }
  }

  const float bias = ld1(bih + row) + ld1(bhh + row);
  // Unified activation: act(x) = A + B * rcp(exp(M*x) + 1)
  //   sigmoid: A=0, B=1,  M=-1 ;  tanh (g==2): A=1, B=-2, M=2
  const bool isg = (g == 2);
  const float Au = isg ? 1.f : 0.f;
  const float Bu = isg ? -2.f : 1.f;
  const float Mu = isg ? 2.f : -1.f;

  float hcur = 0.f, ccur = 0.f;
  if (!first) {
    hcur = hstate[(size_t)bc * NH + unit];
    ccur = cstate[(size_t)bc * NH + unit];
  }
  if (g == 0) hpk[0][unit] = f2bf(hcur);
  __syncthreads();

  const GXT* gxc = gx + (size_t)bc * Tc * NG + row;
  const int nsteps = tend - t_base;
  float g_cur = (0 < nsteps) ? ld1(gxc) : 0.f;
  float g_n1 = (1 < nsteps) ? ld1(gxc + NG) : 0.f;

  for (int s = 0; s < nsteps; ++s) {
    float g_n2 = (s + 2 < nsteps) ? ld1(gxc + (size_t)(s + 2) * NG) : 0.f;

    const uint4* hb = (const uint4*)hpk[s & 1];
    float a0 = 0.f, a1 = 0.f, a2 = 0.f, a3 = 0.f;
#pragma unroll
    for (int i = 0; i < 16; ++i) {
      uint4 hv = hb[i];  // broadcast ds_read_b128
      a0 = dot2bf(w2[4 * i + 0], hv.x, a0);
      a1 = dot2bf(w2[4 * i + 1], hv.y, a1);
      a2 = dot2bf(w2[4 * i + 2], hv.z, a2);
      a3 = dot2bf(w2[4 * i + 3], hv.w, a3);
    }
    const float gate = g_cur + bias + ((a0 + a1) + (a2 + a3));
    const float v = fmaf(Bu, __builtin_amdgcn_rcpf(__expf(Mu * gate) + 1.f), Au);

    // Gather the 4 gates of this unit into the g==0 lanes.
    const float x1 = __shfl_xor(v, 16, 64);   // g0 <- f
    const float x2 = __shfl_xor(v, 32, 64);   // g0 <- g~
    const float x3 = __shfl_xor(x1, 32, 64);  // g0 <- o
    // (only meaningful in g==0 lanes; others compute garbage, never stored)
    ccur = fmaf(x1, ccur, v * x2);            // c = f*c + i*g~
    hcur = x3 * tanh_fast(ccur);              // h = o*tanh(c)
    if (g == 0) hpk[(s + 1) & 1][unit] = f2bf(hcur);
    __syncthreads();

    g_cur = g_n1;
    g_n1 = g_n2;
  }

  if (!last) {
    if (g == 0) {
      hstate[(size_t)bc * NH + unit] = hcur;
      cstate[(size_t)bc * NH + unit] = ccur;
    }
  } else {
    if (g == 0) hf[unit] = hcur;
    __syncthreads();
    if (tid < NC) {
      float acc = ld1(fcb + tid);
      const XT* wv = fcw + (size_t)tid * NH;
#pragma unroll
      for (int k = 0; k < NH; ++k) acc = fmaf(ld1(wv + k), hf[k], acc);
      st1(out + (size_t)b * NC + tid, acc);
    }
  }
}

// ---------------------------------------------------------------------------
template <typename XT, typename GXT>
static void run_variant(int want, const int* flag, void* const* d_in, XT* out,
                        GXT* gx, float* hstate, float* cstate, int NBc, int Tc,
                        hipStream_t stream) {
  const XT* X = (const XT*)d_in[0];
  const XT* Wih = (const XT*)d_in[1];
  const XT* Whh = (const XT*)d_in[2];
  const XT* bih = (const XT*)d_in[3];
  const XT* bhh = (const XT*)d_in[4];
  const XT* fcw = (const XT*)d_in[5];
  const XT* fcb = (const XT*)d_in[6];
  const int* lengths = (const int*)d_in[7];
  for (int bb = 0; bb < NB; bb += NBc) {
    for (int tb = 0; tb < NT; tb += Tc) {
      gx_gemm<XT, GXT><<<dim3((NBc * Tc) / 128), dim3(256), 0, stream>>>(
          flag, want, X, Wih, lengths, gx, bb, tb, Tc);
      lstm_rec<XT, GXT><<<dim3(NBc), dim3(512), 0, stream>>>(
          flag, want, gx, Whh, bih, bhh, fcw, fcb, lengths, out, hstate, cstate, bb, tb, Tc);
    }
  }
}

extern "C" void kernel_launch(void* const* d_in, const int* in_sizes, int n_in,
                              void* d_out, int out_size, void* d_ws, size_t ws_size,
                              hipStream_t stream) {
  int* flag = (int*)d_ws;
  detect_dtype<<<dim3(1), dim3(64), 0, stream>>>((const unsigned short*)d_in[0], flag);

  const size_t full_f32 = (size_t)NB * NT * NG * sizeof(float);
  const size_t full_bf16 = (size_t)NB * NT * NG * 2;
  const size_t base = 512;

  int NBc, Tc;
  char* gx_raw;
  float* hstate = (float*)((char*)d_ws + base);
  bool gx_is_f32;

  if (ws_size >= base + full_f32) {
    NBc = NB; Tc = NT; gx_is_f32 = true;
    gx_raw = (char*)d_ws + base;
  } else if (ws_size >= base + full_bf16) {
    NBc = NB; Tc = NT; gx_is_f32 = false;
    gx_raw = (char*)d_ws + base;
  } else {
    Tc = 128; gx_is_f32 = false;
    NBc = 1;
    for (int cand : {64, 16, 4}) {
      size_t need = base + (size_t)cand * NH * 2 * sizeof(float) + (size_t)cand * Tc * NG * 2;
      if (ws_size >= need) { NBc = cand; break; }
    }
    gx_raw = (char*)d_ws + base + (size_t)NBc * NH * 2 * sizeof(float);
  }
  float* cstate = hstate + (size_t)NBc * NH;

  if (gx_is_f32) {
    run_variant<unsigned short, float>(0, flag, d_in, (unsigned short*)d_out,
                                       (float*)gx_raw, hstate, cstate, NBc, Tc, stream);
    run_variant<float, float>(1, flag, d_in, (float*)d_out, (float*)gx_raw, hstate,
                              cstate, NBc, Tc, stream);
  } else {
    run_variant<unsigned short, unsigned short>(0, flag, d_in, (unsigned short*)d_out,
                                                (unsigned short*)gx_raw, hstate, cstate,
                                                NBc, Tc, stream);
    run_variant<float, unsigned short>(1, flag, d_in, (float*)d_out,
                                       (unsigned short*)gx_raw, hstate, cstate, NBc, Tc,
                                       stream);
  }
}